// Round 1
// 275.391 us; speedup vs baseline: 1.0002x; 1.0002x over previous
//
#include <hip/hip_runtime.h>
#include <hip/hip_bf16.h>
#include <math.h>

#define W_    384
#define H_    384
#define HW_   (384*384)
#define C_    256
#define NOBJ  16
#define NP    128
#define N2    2048
#define NF1   (NOBJ*NP)            // 2048 key points
#define NPTS  (NOBJ*NP + NOBJ*N2)  // 34816 total sampled points
#define NG    16                   // n-groups of 128 in simdist
#define NT    8                    // 16-wide n-tiles per group

typedef __attribute__((ext_vector_type(8))) short short8;
typedef __attribute__((ext_vector_type(4))) float f32x4;

__device__ __forceinline__ unsigned short f2bf(float v) {
    unsigned int u = __float_as_uint(v);
    u += 0x7fffu + ((u >> 16) & 1u);            // RNE f32->bf16
    return (unsigned short)(u >> 16);
}

__device__ __forceinline__ void gload_lds16(const void* g, void* l) {
    // async 16B/lane global->LDS DMA; LDS dest = wave-uniform base + lane*16
    __builtin_amdgcn_global_load_lds(
        (const __attribute__((address_space(1))) void*)g,
        (__attribute__((address_space(3))) void*)l, 16, 0, 0);
}

// ---------------------------------------------------------------------------
// Kernel 1: transpose feats [C,H,W] f32 -> ftT [H*W, C] bf16.
// 64ch x 64pos tile. Phase 1: global_load_lds (16B/lane, no VGPR roundtrip)
// into linear [64][64] f32 LDS. Bank-conflict fix per both-sides rule: the
// p-index is XOR-swizzled by c bits 3..4 on the GLOBAL SOURCE address
// (p ^= ((c>>3)&3)<<3; a 16B chunk permutation within each 256B row, same
// cachelines fetched), and the same XOR is applied on the phase-2 read.
// Phase 2 column read then hits bank b' | 8*(w ^ (lane&3)) -> exact 2-way
// aliasing = free. Output is bit-identical to the previous version.
// HBM-bound floor: 151 MB read + 75.5 MB write ~= 36 us.
// ---------------------------------------------------------------------------
__global__ __launch_bounds__(256) void k_transpose(const float* __restrict__ feats,
                                                   unsigned short* __restrict__ ftT) {
    __shared__ float tile[64 * 64];             // linear, unpadded (DMA dest)
    int b     = blockIdx.x;
    int pbase = (b % (HW_ / 64)) * 64;
    int cbase = (b / (HW_ / 64)) * 64;
    int t     = threadIdx.x;
    int l     = t & 63;
    int w     = t >> 6;

    #pragma unroll
    for (int pass = 0; pass < 4; ++pass) {
        int c    = pass * 16 + w * 4 + (l >> 4);            // row 0..63
        int psrc = ((l & 15) * 4) ^ (((c >> 3) & 3) << 3);  // swizzled source p
        const float* src = feats + (size_t)(cbase + c) * HW_ + pbase + psrc;
        float* dst = &tile[pass * 1024 + w * 256];          // wave-uniform base
        gload_lds16(src, dst);
    }
    asm volatile("s_waitcnt vmcnt(0)" ::: "memory");
    __syncthreads();

    int c8  = (t & 7) * 8;
    int p0  = t >> 3;                           // 0..31
    int swz = (t & 3) << 3;                     // ((c8+j)>>3)&3 == t&3, j-invariant
    #pragma unroll
    for (int pass = 0; pass < 2; ++pass) {
        int p   = p0 + pass * 32;
        int psw = p ^ swz;
        unsigned short u[8];
        #pragma unroll
        for (int j = 0; j < 8; ++j) u[j] = f2bf(tile[(c8 + j) * 64 + psw]);
        uint4 pk;
        pk.x = (unsigned)u[0] | ((unsigned)u[1] << 16);
        pk.y = (unsigned)u[2] | ((unsigned)u[3] << 16);
        pk.z = (unsigned)u[4] | ((unsigned)u[5] << 16);
        pk.w = (unsigned)u[6] | ((unsigned)u[7] << 16);
        *(uint4*)(ftT + (size_t)(pbase + p) * C_ + cbase + c8) = pk;
    }
}

// ---------------------------------------------------------------------------
// Kernel 2: bilinear sample -> f12 [NPTS, C] bf16 (rows 0..2047 = f1 from
// key_points, rows 2048.. = f2 from point_set_2). Two points per wave:
// 32 lanes x 8 channels, 16 B/lane loads/stores (512 B per tap row).
// ---------------------------------------------------------------------------
__global__ __launch_bounds__(256) void k_sample(const float* __restrict__ kpts,
                                                const float* __restrict__ ps2,
                                                const unsigned short* __restrict__ ftT,
                                                unsigned short* __restrict__ f12) {
    int wave  = blockIdx.x * 4 + (threadIdx.x >> 6);
    int lane  = threadIdx.x & 63;
    int half  = lane >> 5;
    int l32   = lane & 31;
    int point = wave * 2 + half;
    int cb    = l32 * 8;

    const float* src = (point < NF1) ? (kpts + (size_t)point * 2)
                                     : (ps2 + (size_t)(point - NF1) * 2);
    // img_size == (W,H): normalization cancels; align_corners=False => -0.5
    float x  = src[0] - 0.5f;
    float y  = src[1] - 0.5f;
    float x0 = floorf(x), y0 = floorf(y);
    int ix0 = (int)x0, iy0 = (int)y0;
    float fx = x - x0, fy = y - y0;

    float a[8] = {0.f, 0.f, 0.f, 0.f, 0.f, 0.f, 0.f, 0.f};
    #pragma unroll
    for (int dy = 0; dy < 2; ++dy) {
        #pragma unroll
        for (int dx = 0; dx < 2; ++dx) {
            int ix = ix0 + dx, iy = iy0 + dy;
            float w = (dx ? fx : 1.f - fx) * (dy ? fy : 1.f - fy);
            if (ix >= 0 && ix < W_ && iy >= 0 && iy < H_) {   // half-wave uniform
                uint4 tv = *(const uint4*)(ftT + ((size_t)(iy * W_ + ix) * C_ + cb));
                a[0] += w * __uint_as_float(tv.x << 16);
                a[1] += w * __uint_as_float(tv.x & 0xffff0000u);
                a[2] += w * __uint_as_float(tv.y << 16);
                a[3] += w * __uint_as_float(tv.y & 0xffff0000u);
                a[4] += w * __uint_as_float(tv.z << 16);
                a[5] += w * __uint_as_float(tv.z & 0xffff0000u);
                a[6] += w * __uint_as_float(tv.w << 16);
                a[7] += w * __uint_as_float(tv.w & 0xffff0000u);
            }
        }
    }
    uint4 pk;
    pk.x = (unsigned)f2bf(a[0]) | ((unsigned)f2bf(a[1]) << 16);
    pk.y = (unsigned)f2bf(a[2]) | ((unsigned)f2bf(a[3]) << 16);
    pk.z = (unsigned)f2bf(a[4]) | ((unsigned)f2bf(a[5]) << 16);
    pk.w = (unsigned)f2bf(a[6]) | ((unsigned)f2bf(a[7]) << 16);
    *(uint4*)(f12 + (size_t)point * C_ + cb) = pk;
}

// Fallback sampler (no transposed copy): gathers straight from [C,H,W] f32.
__global__ __launch_bounds__(256) void k_sample_direct(const float* __restrict__ kpts,
                                                       const float* __restrict__ ps2,
                                                       const float* __restrict__ feats,
                                                       unsigned short* __restrict__ f12) {
    int point = blockIdx.x * 4 + (threadIdx.x >> 6);
    int lane  = threadIdx.x & 63;
    int cb    = lane * 4;

    const float* src = (point < NF1) ? (kpts + (size_t)point * 2)
                                     : (ps2 + (size_t)(point - NF1) * 2);
    float x  = src[0] - 0.5f, y = src[1] - 0.5f;
    float x0 = floorf(x), y0 = floorf(y);
    int ix0 = (int)x0, iy0 = (int)y0;
    float fx = x - x0, fy = y - y0;

    float acc[4] = {0.f, 0.f, 0.f, 0.f};
    #pragma unroll
    for (int dy = 0; dy < 2; ++dy) {
        #pragma unroll
        for (int dx = 0; dx < 2; ++dx) {
            int ix = ix0 + dx, iy = iy0 + dy;
            float w = (dx ? fx : 1.f - fx) * (dy ? fy : 1.f - fy);
            if (ix >= 0 && ix < W_ && iy >= 0 && iy < H_) {
                int base = iy * W_ + ix;
                #pragma unroll
                for (int u = 0; u < 4; ++u)
                    acc[u] += w * feats[(size_t)(cb + u) * HW_ + base];
            }
        }
    }
    ushort4 o;
    o.x = f2bf(acc[0]); o.y = f2bf(acc[1]); o.z = f2bf(acc[2]); o.w = f2bf(acc[3]);
    *(ushort4*)(f12 + (size_t)point * C_ + cb) = o;
}

// ---------------------------------------------------------------------------
// Kernel 3: bf16 MFMA sign-dot + masked distance stats.
// One wave per (o, 16-p tile, 128-n group). A-frags (full K=256) in 32 VGPRs.
// B-frags explicitly double-buffered (b0/b1 ping-pong, statically indexed):
// tile t+1's 8 loads issue before tile t's MFMA chain, hiding L2/L3 latency
// at the 2-waves/SIMD occupancy this grid gives. MFMA order unchanged ->
// bit-identical results. Partials layout [o][p][g] for coalesced k_final.
// MFMA layouts per m89: C/D col=lane&15, row=(lane>>4)*4+reg;
// A/B m(n)=lane&15, k=(lane>>4)*8+j.
// ---------------------------------------------------------------------------
__device__ __forceinline__ void bload(const short* bbase, int t, short8* dst) {
    const short8* bp = (const short8*)(bbase + (size_t)t * 16 * C_);
    #pragma unroll
    for (int kb = 0; kb < 8; ++kb) dst[kb] = bp[kb * 4];   // +32 bf16 per block
}

__global__ __launch_bounds__(256) void k_simdist(const unsigned short* __restrict__ f12,
                                                 const float* __restrict__ ps1,
                                                 const float* __restrict__ ps2,
                                                 float* __restrict__ pmin,
                                                 float* __restrict__ psum,
                                                 float* __restrict__ pcnt) {
    int wid  = blockIdx.x * 4 + (threadIdx.x >> 6);   // 0..2047
    int lane = threadIdx.x & 63;
    int ng = wid & 15;
    int pt = (wid >> 4) & 7;
    int o  = wid >> 7;
    int quad = lane >> 4, col = lane & 15;

    const short* f12s = (const short*)f12;
    const short8* aptr =
        (const short8*)(f12s + ((size_t)(o * NP + pt * 16 + col) * C_ + quad * 8));
    short8 a[8];
    #pragma unroll
    for (int kb = 0; kb < 8; ++kb) a[kb] = aptr[kb * 4];

    const short* bbase = f12s + ((size_t)(NF1 + o * N2 + ng * 128 + col) * C_ + quad * 8);

    const float2* ps1v = (const float2*)ps1;
    const float2* ps2v = (const float2*)ps2;
    float pxr[4], pyr[4];
    #pragma unroll
    for (int r = 0; r < 4; ++r) {
        float2 pc = ps1v[o * NP + pt * 16 + quad * 4 + r];
        pxr[r] = pc.x; pyr[r] = pc.y;
    }

    float mn[4] = {INFINITY, INFINITY, INFINITY, INFINITY};
    float sm[4] = {0.f, 0.f, 0.f, 0.f};
    float ct[4] = {0.f, 0.f, 0.f, 0.f};

    auto ctile = [&](int t, short8 (&b)[8]) {
        f32x4 acc = {0.f, 0.f, 0.f, 0.f};
        #pragma unroll
        for (int kb = 0; kb < 8; ++kb)
            acc = __builtin_amdgcn_mfma_f32_16x16x32_bf16(a[kb], b[kb], acc, 0, 0, 0);
        float2 nc = ps2v[o * N2 + ng * 128 + t * 16 + col];  // this lane's n-column
        #pragma unroll
        for (int r = 0; r < 4; ++r) {
            if (acc[r] >= 0.f) {                  // sims >= 0  <=>  dot >= 0
                float dx = pxr[r] - nc.x, dy = pyr[r] - nc.y;
                float d  = sqrtf(dx * dx + dy * dy);
                mn[r] = fminf(mn[r], d); sm[r] += d; ct[r] += 1.f;
            }
        }
    };

    short8 b0[8], b1[8];
    bload(bbase, 0, b0);
    for (int t = 0; t < NT; t += 2) {             // NT even: clean ping-pong
        bload(bbase, t + 1, b1);
        ctile(t, b0);
        if (t + 2 < NT) bload(bbase, t + 2, b0);
        ctile(t + 1, b1);
    }

    #pragma unroll
    for (int r = 0; r < 4; ++r) {
        #pragma unroll
        for (int off = 1; off < 16; off <<= 1) {
            mn[r] = fminf(mn[r], __shfl_xor(mn[r], off, 16));
            sm[r] += __shfl_xor(sm[r], off, 16);
            ct[r] += __shfl_xor(ct[r], off, 16);
        }
    }
    if (col == 0) {
        #pragma unroll
        for (int r = 0; r < 4; ++r) {
            int p   = pt * 16 + quad * 4 + r;
            int idx = (o * NP + p) * NG + ng;     // [o][p][g]
            pmin[idx] = mn[r]; psum[idx] = sm[r]; pcnt[idx] = ct[r];
        }
    }
}

// ---------------------------------------------------------------------------
// Kernel 4: combine group partials -> scalar loss. 1024 threads, contiguous
// 64 B reads per (o,p) pair. (Unchanged: keeps reduction order, and thus the
// output, bit-identical.)
// ---------------------------------------------------------------------------
__global__ __launch_bounds__(1024) void k_final(const float* __restrict__ pmin,
                                                const float* __restrict__ psum,
                                                const float* __restrict__ pcnt,
                                                float* __restrict__ out) {
    int t = threadIdx.x;
    float tot = 0.f;
    for (int pair = t; pair < NOBJ * NP; pair += 1024) {
        int base = pair * NG;
        const float4* pm = (const float4*)(pmin + base);
        const float4* ps = (const float4*)(psum + base);
        const float4* pc = (const float4*)(pcnt + base);
        float mn = INFINITY, sm = 0.f, ct = 0.f;
        #pragma unroll
        for (int g4 = 0; g4 < 4; ++g4) {
            float4 a = pm[g4], b = ps[g4], c = pc[g4];
            mn = fminf(mn, fminf(fminf(a.x, a.y), fminf(a.z, a.w)));
            sm += b.x + b.y + b.z + b.w;
            ct += c.x + c.y + c.z + c.w;
        }
        if (ct > 0.f) tot += 0.5f * (mn + sm / ct);
    }
    #pragma unroll
    for (int off = 32; off; off >>= 1) tot += __shfl_xor(tot, off, 64);
    __shared__ float wsum[16];
    if ((t & 63) == 0) wsum[t >> 6] = tot;
    __syncthreads();
    if (t < 64) {
        float v = (t < 16) ? wsum[t] : 0.f;
        #pragma unroll
        for (int off = 8; off; off >>= 1) v += __shfl_xor(v, off, 16);
        if (t == 0) out[0] = v * (1.0f / (NOBJ * NP));
    }
}

// ---------------------------------------------------------------------------
extern "C" void kernel_launch(void* const* d_in, const int* in_sizes, int n_in,
                              void* d_out, int out_size, void* d_ws, size_t ws_size,
                              hipStream_t stream) {
    const float* ps1   = (const float*)d_in[0];  // [16,128,2]
    const float* ps2   = (const float*)d_in[1];  // [16,2048,2]
    const float* feats = (const float*)d_in[2];  // [1,256,384,384]
    const float* kpts  = (const float*)d_in[3];  // [2048,2]
    float* out = (float*)d_out;

    const size_t sz_ftT  = (size_t)HW_ * C_ * sizeof(unsigned short);   // 75,497,472
    const size_t sz_f12  = (size_t)NPTS * C_ * sizeof(unsigned short);  // 17,825,792
    const size_t sz_part = (size_t)NOBJ * NP * NG * sizeof(float);      //    131,072

    char* ws = (char*)d_ws;
    if (ws_size >= sz_ftT + sz_f12 + 3 * sz_part) {
        unsigned short* ftT = (unsigned short*)ws;
        unsigned short* f12 = (unsigned short*)(ws + sz_ftT);
        float* pmin = (float*)(ws + sz_ftT + sz_f12);
        float* psum = (float*)(ws + sz_ftT + sz_f12 + sz_part);
        float* pcnt = (float*)(ws + sz_ftT + sz_f12 + 2 * sz_part);

        k_transpose<<<(HW_ / 64) * (C_ / 64), 256, 0, stream>>>(feats, ftT);
        k_sample<<<NPTS / 8, 256, 0, stream>>>(kpts, ps2, ftT, f12);
        k_simdist<<<NOBJ * 8 * NG / 4, 256, 0, stream>>>(f12, ps1, ps2, pmin, psum, pcnt);
        k_final<<<1, 1024, 0, stream>>>(pmin, psum, pcnt, out);
    } else {
        // Fallback: no transposed feature copy (uncoalesced gathers, but correct).
        unsigned short* f12 = (unsigned short*)ws;
        float* pmin = (float*)(ws + sz_f12);
        float* psum = (float*)(ws + sz_f12 + sz_part);
        float* pcnt = (float*)(ws + sz_f12 + 2 * sz_part);

        k_sample_direct<<<NPTS / 4, 256, 0, stream>>>(kpts, ps2, feats, f12);
        k_simdist<<<NOBJ * 8 * NG / 4, 256, 0, stream>>>(f12, ps1, ps2, pmin, psum, pcnt);
        k_final<<<1, 1024, 0, stream>>>(pmin, psum, pcnt, out);
    }
}